// Round 6
// baseline (213.258 us; speedup 1.0000x reference)
//
#include <hip/hip_runtime.h>
#include <cstddef>
#include <cstdint>

#define Mq   2048      // B*P
#define Lq   30
#define N1q  1024      // FH
#define N2q  512       // FH/2
#define K1q  1536      // 2*H
#define Hq   768
#define NBLK 512       // loss blocks

typedef float    f32x4 __attribute__((ext_vector_type(4)));
typedef _Float16 f16x8 __attribute__((ext_vector_type(8)));

#define GLD16(gptr, lptr) \
  __builtin_amdgcn_global_load_lds((const __attribute__((address_space(1))) void*)(gptr), \
                                   (__attribute__((address_space(3))) void*)(lptr), 16, 0, 0)

// ---------- prep_all ----------
// [0,256)   gather -> A1 f16
// [256,640) W1T transpose (f32 -> f16)
// [640,760) W23T = (W2 @ W3)^T, f32  -- head is LINEAR (LeakyReLU slope 1.0), so
//           gemm2 is folded away: logits = h1 @ W23 + beff
// [760]     beff = b2 @ W3 + b3
__device__ void transpose_tile(const float* __restrict__ src,
                               _Float16* __restrict__ dst,
                               int K, int N, int k0, int n0) {
  __shared__ float T[64][65];
  const int t = threadIdx.x;
  {
    const int kl = t >> 2, nc = (t & 3) * 16;
    const float* s = src + (size_t)(k0 + kl) * N + n0 + nc;
    float4 v0 = *(const float4*)s;
    float4 v1 = *(const float4*)(s + 4);
    float4 v2 = *(const float4*)(s + 8);
    float4 v3 = *(const float4*)(s + 12);
    T[nc + 0][kl] = v0.x; T[nc + 1][kl] = v0.y; T[nc + 2][kl] = v0.z; T[nc + 3][kl] = v0.w;
    T[nc + 4][kl] = v1.x; T[nc + 5][kl] = v1.y; T[nc + 6][kl] = v1.z; T[nc + 7][kl] = v1.w;
    T[nc + 8][kl] = v2.x; T[nc + 9][kl] = v2.y; T[nc +10][kl] = v2.z; T[nc +11][kl] = v2.w;
    T[nc +12][kl] = v3.x; T[nc +13][kl] = v3.y; T[nc +14][kl] = v3.z; T[nc +15][kl] = v3.w;
  }
  __syncthreads();
  {
    const int nl = t >> 2, kc = (t & 3) * 16;
    __align__(16) _Float16 tmp[16];
    #pragma unroll
    for (int i = 0; i < 16; ++i) tmp[i] = (_Float16)T[nl][kc + i];
    _Float16* d = dst + (size_t)(n0 + nl) * K + k0 + kc;
    *(uint4*)d       = *(const uint4*)tmp;
    *(uint4*)(d + 8) = *(const uint4*)(tmp + 8);
  }
}

__global__ __launch_bounds__(256)
void prep_all(const float* __restrict__ tok, const float* __restrict__ pool,
              const int* __restrict__ npos, const float* __restrict__ W1,
              const float* __restrict__ W2, const float* __restrict__ W3,
              const float* __restrict__ b2, const float* __restrict__ b3,
              _Float16* __restrict__ A1, _Float16* __restrict__ W1T,
              float* __restrict__ W23T, float* __restrict__ beff) {
  const int bid = blockIdx.x, tid = threadIdx.x;
  if (bid < 256) {
    const int q = tid >> 5, l32 = tid & 31;
    const int m = bid * 8 + q;
    const int bI = m >> 5, p = m & 31;
    const int pos = npos[bI * 32 + p];
    const float* src1 = tok + ((size_t)bI * 512 + pos) * Hq;
    const float* src2 = pool + (size_t)bI * Hq;
    _Float16* dst = A1 + (size_t)m * K1q;
    for (int g = l32; g < 384; g += 32) {
      const float* s = (g < 192) ? (src1 + g * 4) : (src2 + (g - 192) * 4);
      float4 v = *(const float4*)s;
      __align__(8) _Float16 o[4] = {(_Float16)v.x, (_Float16)v.y, (_Float16)v.z, (_Float16)v.w};
      *(uint2*)(dst + g * 4) = *(const uint2*)o;
    }
  } else if (bid < 640) {
    const int idx = bid - 256;               // 24 k-tiles x 16 n-tiles
    transpose_tile(W1, W1T, K1q, N1q, (idx / 16) * 64, (idx % 16) * 64);
  } else if (bid < 760) {
    // W23T[c][k] = sum_j W2[k][j] * W3[j][c]   (k in 1024, c in 30, j in 512)
    // one output per thread; consecutive tid -> c fastest (W3 reads coalesced,
    // W2 row broadcast within wave), all f32 for accuracy.
    const int idx = (bid - 640) * 256 + tid;  // 120*256 = 30720 = 1024*30
    const int k = idx / Lq, c = idx - k * Lq;
    const float* w2r = W2 + (size_t)k * N2q;
    float s0 = 0.f, s1 = 0.f, s2 = 0.f, s3 = 0.f;
    #pragma unroll 4
    for (int j = 0; j < N2q; j += 4) {
      const float4 wv = *(const float4*)(w2r + j);
      s0 = fmaf(wv.x, W3[(size_t)(j)     * Lq + c], s0);
      s1 = fmaf(wv.y, W3[(size_t)(j + 1) * Lq + c], s1);
      s2 = fmaf(wv.z, W3[(size_t)(j + 2) * Lq + c], s2);
      s3 = fmaf(wv.w, W3[(size_t)(j + 3) * Lq + c], s3);
    }
    W23T[(size_t)c * N1q + k] = (s0 + s1) + (s2 + s3);
  } else {
    // beff[c] = b3[c] + sum_j b2[j] * W3[j][c]; 240 threads = 30 c x 8 j-chunks
    __shared__ float R[8][32];
    const int c = tid % Lq, jc = tid / Lq;     // jc in [0,8) for tid<240
    float s = 0.f;
    if (tid < 240) {
      for (int j = jc * 64; j < jc * 64 + 64; ++j)
        s = fmaf(b2[j], W3[(size_t)j * Lq + c], s);
      R[jc][c] = s;
    }
    __syncthreads();
    if (tid < Lq) {
      float t0 = b3[tid];
      #pragma unroll
      for (int g = 0; g < 8; ++g) t0 += R[g][tid];
      beff[tid] = t0;
    }
  }
}

// ---------- gemm1: A1[2048][1536] f16 @ W1T[1024][1536] -> C1 = h1+b1 (f16)
// 64x64 tile, BK=64, grid (16 n, 32 m) = 512 blocks (2 blocks/CU), depth-1 dbuf.
// NOTE: compiler-scheduled prefetch-1 + __syncthreads. Hand-rolled counted-vmcnt
// ring-3 pipeline measured NEUTRAL (R3 vs R4) - no reason to reintroduce.
__global__ __launch_bounds__(256)
void gemm1_k(const _Float16* __restrict__ A, const _Float16* __restrict__ BT,
             const float* __restrict__ b1, _Float16* __restrict__ C1) {
  __shared__ _Float16 As[2][64 * 64];
  __shared__ _Float16 Bs[2][64 * 64];
  const int tid = threadIdx.x, w = tid >> 6, lane = tid & 63;
  const int n0 = blockIdx.x * 64, m0 = blockIdx.y * 64;
  const int ml = lane & 15, g4 = lane >> 4;
  const int wm = (w >> 1) * 32, wn = (w & 1) * 32;
  const int lr = lane >> 3, lc = lane & 7;   // staging: row-in-8, 16B chunk

  f32x4 acc[2][2];
  #pragma unroll
  for (int i = 0; i < 2; ++i)
    #pragma unroll
    for (int j = 0; j < 2; ++j)
      #pragma unroll
      for (int r = 0; r < 4; ++r) acc[i][j][r] = 0.f;

  auto stage = [&](int it, int b) {
    const int kt = it * 64;
    #pragma unroll
    for (int t = 0; t < 2; ++t) {
      const int r  = w * 16 + t * 8 + lr;
      const int cs = lc ^ (r & 7);           // pre-swizzled source chunk
      GLD16(A  + (size_t)(m0 + r) * K1q + kt + cs * 8, &As[b][(w * 16 + t * 8) * 64]);
      GLD16(BT + (size_t)(n0 + r) * K1q + kt + cs * 8, &Bs[b][(w * 16 + t * 8) * 64]);
    }
  };

  stage(0, 0);
  __syncthreads();
  #pragma unroll 1
  for (int it = 0; it < 24; ++it) {
    const int cur = it & 1;
    if (it < 23) stage(it + 1, cur ^ 1);
    f16x8 af[2][2], bf[2][2];
    #pragma unroll
    for (int i = 0; i < 2; ++i) {
      const int ar = wm + i * 16 + ml;
      const int br = wn + i * 16 + ml;
      #pragma unroll
      for (int ks = 0; ks < 2; ++ks) {
        af[i][ks] = *(const f16x8*)&As[cur][ar * 64 + (((ks * 4 + g4) ^ (ar & 7)) << 3)];
        bf[i][ks] = *(const f16x8*)&Bs[cur][br * 64 + (((ks * 4 + g4) ^ (br & 7)) << 3)];
      }
    }
    #pragma unroll
    for (int i = 0; i < 2; ++i)
      #pragma unroll
      for (int j = 0; j < 2; ++j)
        #pragma unroll
        for (int ks = 0; ks < 2; ++ks)
          acc[i][j] = __builtin_amdgcn_mfma_f32_16x16x32_f16(bf[j][ks], af[i][ks], acc[i][j], 0, 0, 0);
    __syncthreads();
  }

  #pragma unroll
  for (int i = 0; i < 2; ++i) {
    const int row = m0 + wm + i * 16 + ml;
    #pragma unroll
    for (int j = 0; j < 2; ++j) {
      const int col = n0 + wn + j * 16 + g4 * 4;
      const float4 bv = *(const float4*)(b1 + col);
      __align__(8) _Float16 o[4] = {(_Float16)(acc[i][j][0] + bv.x),
                                    (_Float16)(acc[i][j][1] + bv.y),
                                    (_Float16)(acc[i][j][2] + bv.z),
                                    (_Float16)(acc[i][j][3] + bv.w)};
      *(uint2*)(C1 + (size_t)row * N1q + col) = *(const uint2*)o;
    }
  }
}

// ---------- logits + fused loss: logit = h1 @ W23 + beff  (gemm2 folded away)
// 4 rows/block, one 5-float partial per block. K=1024, W23T rows contiguous.
__global__ __launch_bounds__(256)
void loss_kernel(const _Float16* __restrict__ C1, const float* __restrict__ W23T,
                 const float* __restrict__ beff, const float* __restrict__ labels,
                 float* __restrict__ part) {
  __shared__ float hrow[4][1024];
  __shared__ float red[4][5];
  const int tid = threadIdx.x, w = tid >> 6, lane = tid & 63;
  const int m = blockIdx.x * 4 + w;

  {
    const int k = lane * 16;                       // 64 lanes x 16 elems = 1024
    const _Float16* cp = C1 + (size_t)m * N1q + k;
    f16x8 v0 = *(const f16x8*)cp;
    f16x8 v1 = *(const f16x8*)(cp + 8);
    #pragma unroll
    for (int e = 0; e < 8; ++e) {
      hrow[w][k + e]     = (float)v0[e];
      hrow[w][k + 8 + e] = (float)v1[e];
    }
  }
  __syncthreads();

  const int c  = lane & 31;
  const int kh = lane >> 5;
  float a0 = 0.f, a1 = 0.f, a2 = 0.f, a3 = 0.f;
  if (c < Lq) {
    const float* hp = hrow[w] + kh * 512;
    const float* wp = W23T + (size_t)c * N1q + kh * 512;   // contiguous row
    #pragma unroll 4
    for (int i = 0; i < 512; i += 4) {
      const float4 wv = *(const float4*)(wp + i);
      a0 = fmaf(hp[i],     wv.x, a0);
      a1 = fmaf(hp[i + 1], wv.y, a1);
      a2 = fmaf(hp[i + 2], wv.z, a2);
      a3 = fmaf(hp[i + 3], wv.w, a3);
    }
  }
  float a = (a0 + a1) + (a2 + a3);
  a += __shfl_xor(a, 32);

  const bool act = lane < Lq;
  float logit = 0.f, lab = 0.f;
  if (act) {
    logit = a + beff[lane];
    lab = labels[(size_t)m * Lq + lane];
  }

  const unsigned long long validmask = __ballot(act && lab != -1.0f);
  const unsigned long long outmask   = __ballot(act && logit > 0.0f);
  const unsigned long long labmask   = __ballot(act && lab == 1.0f);
  const bool valid = (validmask != 0ULL);
  const int count_out = __popcll(outmask);
  const int count_lab = __popcll(labmask);

  float bce = 0.f;
  if (act && valid) {
    const float x = logit;
    bce = fmaxf(x, 0.f) + log1pf(expf(-fabsf(x))) - x * lab;
  }
  bce += __shfl_xor(bce, 16); bce += __shfl_xor(bce, 8);
  bce += __shfl_xor(bce, 4);  bce += __shfl_xor(bce, 2);
  bce += __shfl_xor(bce, 1);

  if (lane == 0) {
    float pb = 0.f, pv = 0.f, pc = 0.f, pe = 0.f, pp = 0.f;
    if (valid) {
      pb = bce; pv = 1.f;
      const float d = (float)count_out - (float)count_lab;
      pc = d * d;
    }
    if (count_out == 1 && count_lab == 1) {
      const float po = (float)(__ffsll((long long)outmask) - 1);
      const float pl = (float)(__ffsll((long long)labmask) - 1);
      pe = 1.f;
      const float dp = po - pl;
      pp = dp * dp;
    }
    red[w][0] = pb; red[w][1] = pv; red[w][2] = pc; red[w][3] = pe; red[w][4] = pp;
  }
  __syncthreads();
  if (tid < 5) {
    part[blockIdx.x * 5 + tid] =
        red[0][tid] + red[1][tid] + red[2][tid] + red[3][tid];
  }
}

// ---------- finalize: sum NBLK 5-float partials -> scalar loss
__global__ __launch_bounds__(256)
void finalize_kernel(const float* __restrict__ part, float* __restrict__ out) {
  __shared__ float red[32][5];
  const int t = threadIdx.x;
  if (t < 160) {
    const int j = t % 5, grp = t / 5;
    float s = 0.f;
    for (int i = grp; i < NBLK; i += 32) s += part[i * 5 + j];
    red[grp][j] = s;
  }
  __syncthreads();
  if (t == 0) {
    float t0 = 0.f, t1 = 0.f, t2 = 0.f, t3 = 0.f, t4 = 0.f;
    #pragma unroll
    for (int g = 0; g < 32; ++g) {
      t0 += red[g][0]; t1 += red[g][1]; t2 += red[g][2];
      t3 += red[g][3]; t4 += red[g][4];
    }
    const float bce = t0 / (t1 * (float)Lq);
    const float cnt = 10.0f * t2 / (float)Mq;
    const float pos = (t3 > 0.f) ? 5.0f * t4 / fmaxf(t3, 1.0f) : 0.f;
    out[0] = bce + cnt + pos;
  }
}

extern "C" void kernel_launch(void* const* d_in, const int* in_sizes, int n_in,
                              void* d_out, int out_size, void* d_ws, size_t ws_size,
                              hipStream_t stream) {
  const float* tok    = (const float*)d_in[0];
  const float* pool   = (const float*)d_in[1];
  const int*   npos   = (const int*)  d_in[2];
  const float* labels = (const float*)d_in[3];
  const float* W1     = (const float*)d_in[4];
  const float* b1     = (const float*)d_in[5];
  const float* W2     = (const float*)d_in[6];
  const float* b2     = (const float*)d_in[7];
  const float* W3     = (const float*)d_in[8];
  const float* b3     = (const float*)d_in[9];
  float* out = (float*)d_out;

  char* ws = (char*)d_ws;
  _Float16* A1   = (_Float16*)(ws + 0x00000000);  // 6 MB   [2048][1536]
  _Float16* W1T  = (_Float16*)(ws + 0x00600000);  // 3 MB   [1024][1536]
  _Float16* C1   = (_Float16*)(ws + 0x00900000);  // 4 MB   [2048][1024] h1+b1
  float*    W23T = (float*)   (ws + 0x00D00000);  // 120 KB [30][1024]  (W2@W3)^T
  float*    beff = (float*)   (ws + 0x00D20000);  // 128 B  b2@W3+b3
  float*    part = (float*)   (ws + 0x00D30000);  // 10 KB  [512][5]

  prep_all<<<761, 256, 0, stream>>>(tok, pool, npos, W1, W2, W3, b2, b3,
                                    A1, W1T, W23T, beff);
  gemm1_k<<<dim3(16, 32), 256, 0, stream>>>(A1, W1T, b1, C1);
  loss_kernel<<<NBLK, 256, 0, stream>>>(C1, W23T, beff, labels, part);
  finalize_kernel<<<1, 256, 0, stream>>>(part, out);
}

// Round 7
// 207.601 us; speedup vs baseline: 1.0272x; 1.0272x over previous
//
#include <hip/hip_runtime.h>
#include <cstddef>
#include <cstdint>

#define Mq   2048      // B*P
#define Lq   30
#define N1q  1024      // FH
#define N2q  512       // FH/2
#define K1q  1536      // 2*H
#define Hq   768
#define NBLK 512       // loss blocks

// Entire head is LINEAR (LeakyReLU slope 1.0 == identity), so:
//   logits = feat @ W123 + btot,  W123 = W1@W2@W3 (1536x30, f32),
//   btot = b1@W2@W3 + b2@W3 + b3.
// This deletes gemm1/gemm2, the f16 gather, and the W1 transpose entirely.
// All matrices k-major ([k][c], c fastest) so the 30 active lanes read
// CONSECUTIVE floats per k -> coalesced (R6 lesson: [c][k] rows = 60-line scatter).

// ---------- prep1: W23 = W2 @ W3 (1024x30), W3 staged in LDS; + beff23 = b2@W3+b3
__global__ __launch_bounds__(256)
void prep1(const float* __restrict__ W2, const float* __restrict__ W3,
           const float* __restrict__ b2, const float* __restrict__ b3,
           float* __restrict__ W23, float* __restrict__ beff23) {
  const int bid = blockIdx.x, tid = threadIdx.x;
  if (bid < 120) {                          // 120*256 = 30720 = 1024*30 outputs
    __shared__ float Ws[7680];              // half of W3: 256 j x 30 c (30 KB)
    const int idx = bid * 256 + tid;
    const int k = idx / Lq, c = idx - k * Lq;
    const float* w2r = W2 + (size_t)k * N2q;
    float s0 = 0.f, s1 = 0.f, s2 = 0.f, s3 = 0.f;
    for (int half = 0; half < 2; ++half) {
      __syncthreads();
      for (int i = tid * 4; i < 7680; i += 1024)        // contiguous 30 KB copy
        *(float4*)&Ws[i] = *(const float4*)&W3[half * 7680 + i];
      __syncthreads();
      const float* w2h = w2r + half * 256;
      #pragma unroll 4
      for (int j = 0; j < 256; j += 4) {
        const float4 wv = *(const float4*)(w2h + j);
        s0 = fmaf(wv.x, Ws[(j    ) * Lq + c], s0);
        s1 = fmaf(wv.y, Ws[(j + 1) * Lq + c], s1);
        s2 = fmaf(wv.z, Ws[(j + 2) * Lq + c], s2);
        s3 = fmaf(wv.w, Ws[(j + 3) * Lq + c], s3);
      }
    }
    W23[idx] = (s0 + s1) + (s2 + s3);       // k-major [1024][30]
  } else {
    // beff23[c] = b3[c] + sum_j b2[j]*W3[j][c]; 240 threads = 30 c x 8 j-chunks
    __shared__ float R[8][32];
    const int c = tid % Lq, jc = tid / Lq;
    if (tid < 240) {
      float s = 0.f;
      for (int j = jc * 64; j < jc * 64 + 64; ++j)
        s = fmaf(b2[j], W3[(size_t)j * Lq + c], s);
      R[jc][c] = s;
    }
    __syncthreads();
    if (tid < Lq) {
      float t = b3[tid];
      #pragma unroll
      for (int g = 0; g < 8; ++g) t += R[g][tid];
      beff23[tid] = t;
    }
  }
}

// ---------- prep2: W123 = W1 @ W23 (1536x30), W23 staged in LDS 4x30KB; + btot
__global__ __launch_bounds__(256)
void prep2(const float* __restrict__ W1, const float* __restrict__ b1,
           const float* __restrict__ W23, const float* __restrict__ beff23,
           float* __restrict__ W123, float* __restrict__ btot) {
  const int bid = blockIdx.x, tid = threadIdx.x;
  if (bid < 180) {                          // 180*256 = 46080 = 1536*30 outputs
    __shared__ float Ws[7680];              // quarter of W23: 256 j x 30 c
    const int idx = bid * 256 + tid;
    const int k = idx / Lq, c = idx - k * Lq;
    const float* w1r = W1 + (size_t)k * N1q;
    float s0 = 0.f, s1 = 0.f, s2 = 0.f, s3 = 0.f;
    for (int ph = 0; ph < 4; ++ph) {
      __syncthreads();
      for (int i = tid * 4; i < 7680; i += 1024)
        *(float4*)&Ws[i] = *(const float4*)&W23[ph * 7680 + i];
      __syncthreads();
      const float* w1h = w1r + ph * 256;
      #pragma unroll 4
      for (int j = 0; j < 256; j += 4) {
        const float4 wv = *(const float4*)(w1h + j);
        s0 = fmaf(wv.x, Ws[(j    ) * Lq + c], s0);
        s1 = fmaf(wv.y, Ws[(j + 1) * Lq + c], s1);
        s2 = fmaf(wv.z, Ws[(j + 2) * Lq + c], s2);
        s3 = fmaf(wv.w, Ws[(j + 3) * Lq + c], s3);
      }
    }
    W123[idx] = (s0 + s1) + (s2 + s3);      // k-major [1536][30]
  } else {
    // btot[c] = beff23[c] + sum_j b1[j]*W23[j][c]; 240 threads = 30 c x 8 chunks
    __shared__ float R[8][32];
    const int c = tid % Lq, jc = tid / Lq;
    if (tid < 240) {
      float s = 0.f;
      for (int j = jc * 128; j < jc * 128 + 128; ++j)
        s = fmaf(b1[j], W23[(size_t)j * Lq + c], s);
      R[jc][c] = s;
    }
    __syncthreads();
    if (tid < Lq) {
      float t = beff23[tid];
      #pragma unroll
      for (int g = 0; g < 8; ++g) t += R[g][tid];
      btot[tid] = t;
    }
  }
}

// ---------- loss: gather feat row (tok[pos] ++ pool) -> dot W123 (K=1536) -> loss
// 4 rows/block, one 5-float partial per block. W123 k-major => coalesced reads.
__global__ __launch_bounds__(256)
void loss_kernel(const float* __restrict__ tok, const float* __restrict__ pool,
                 const int* __restrict__ npos, const float* __restrict__ W123,
                 const float* __restrict__ btot, const float* __restrict__ labels,
                 float* __restrict__ part) {
  __shared__ float hrow[4][1536];
  __shared__ float red[4][5];
  const int tid = threadIdx.x, w = tid >> 6, lane = tid & 63;
  const int m = blockIdx.x * 4 + w;
  const int bI = m >> 5, p = m & 31;

  {
    const int pos = npos[bI * 32 + p];
    const float* src1 = tok + ((size_t)bI * 512 + pos) * Hq;
    const float* src2 = pool + (size_t)bI * Hq;
    for (int g = lane; g < 384; g += 64) {
      const float* s = (g < 192) ? (src1 + g * 4) : (src2 + (g - 192) * 4);
      *(float4*)&hrow[w][g * 4] = *(const float4*)s;
    }
  }
  __syncthreads();

  const int c  = lane & 31;
  const int kh = lane >> 5;
  float a0 = 0.f, a1 = 0.f, a2 = 0.f, a3 = 0.f;
  if (c < Lq) {
    const float* hp = hrow[w] + kh * 768;
    const float* wp = W123 + (size_t)(kh * 768) * Lq + c;   // k-major, coalesced
    #pragma unroll 4
    for (int i = 0; i < 768; i += 4) {
      a0 = fmaf(hp[i],     wp[(i)     * Lq], a0);
      a1 = fmaf(hp[i + 1], wp[(i + 1) * Lq], a1);
      a2 = fmaf(hp[i + 2], wp[(i + 2) * Lq], a2);
      a3 = fmaf(hp[i + 3], wp[(i + 3) * Lq], a3);
    }
  }
  float a = (a0 + a1) + (a2 + a3);
  a += __shfl_xor(a, 32);

  const bool act = lane < Lq;
  float logit = 0.f, lab = 0.f;
  if (act) {
    logit = a + btot[lane];
    lab = labels[(size_t)m * Lq + lane];
  }

  const unsigned long long validmask = __ballot(act && lab != -1.0f);
  const unsigned long long outmask   = __ballot(act && logit > 0.0f);
  const unsigned long long labmask   = __ballot(act && lab == 1.0f);
  const bool valid = (validmask != 0ULL);
  const int count_out = __popcll(outmask);
  const int count_lab = __popcll(labmask);

  float bce = 0.f;
  if (act && valid) {
    const float x = logit;
    bce = fmaxf(x, 0.f) + log1pf(expf(-fabsf(x))) - x * lab;
  }
  bce += __shfl_xor(bce, 16); bce += __shfl_xor(bce, 8);
  bce += __shfl_xor(bce, 4);  bce += __shfl_xor(bce, 2);
  bce += __shfl_xor(bce, 1);

  if (lane == 0) {
    float pb = 0.f, pv = 0.f, pc = 0.f, pe = 0.f, pp = 0.f;
    if (valid) {
      pb = bce; pv = 1.f;
      const float d = (float)count_out - (float)count_lab;
      pc = d * d;
    }
    if (count_out == 1 && count_lab == 1) {
      const float po = (float)(__ffsll((long long)outmask) - 1);
      const float pl = (float)(__ffsll((long long)labmask) - 1);
      pe = 1.f;
      const float dp = po - pl;
      pp = dp * dp;
    }
    red[w][0] = pb; red[w][1] = pv; red[w][2] = pc; red[w][3] = pe; red[w][4] = pp;
  }
  __syncthreads();
  if (tid < 5) {
    part[blockIdx.x * 5 + tid] =
        red[0][tid] + red[1][tid] + red[2][tid] + red[3][tid];
  }
}

// ---------- finalize: sum NBLK 5-float partials -> scalar loss
__global__ __launch_bounds__(256)
void finalize_kernel(const float* __restrict__ part, float* __restrict__ out) {
  __shared__ float red[32][5];
  const int t = threadIdx.x;
  if (t < 160) {
    const int j = t % 5, grp = t / 5;
    float s = 0.f;
    for (int i = grp; i < NBLK; i += 32) s += part[i * 5 + j];
    red[grp][j] = s;
  }
  __syncthreads();
  if (t == 0) {
    float t0 = 0.f, t1 = 0.f, t2 = 0.f, t3 = 0.f, t4 = 0.f;
    #pragma unroll
    for (int g = 0; g < 32; ++g) {
      t0 += red[g][0]; t1 += red[g][1]; t2 += red[g][2];
      t3 += red[g][3]; t4 += red[g][4];
    }
    const float bce = t0 / (t1 * (float)Lq);
    const float cnt = 10.0f * t2 / (float)Mq;
    const float pos = (t3 > 0.f) ? 5.0f * t4 / fmaxf(t3, 1.0f) : 0.f;
    out[0] = bce + cnt + pos;
  }
}

extern "C" void kernel_launch(void* const* d_in, const int* in_sizes, int n_in,
                              void* d_out, int out_size, void* d_ws, size_t ws_size,
                              hipStream_t stream) {
  const float* tok    = (const float*)d_in[0];
  const float* pool   = (const float*)d_in[1];
  const int*   npos   = (const int*)  d_in[2];
  const float* labels = (const float*)d_in[3];
  const float* W1     = (const float*)d_in[4];
  const float* b1     = (const float*)d_in[5];
  const float* W2     = (const float*)d_in[6];
  const float* b2     = (const float*)d_in[7];
  const float* W3     = (const float*)d_in[8];
  const float* b3     = (const float*)d_in[9];
  float* out = (float*)d_out;

  char* ws = (char*)d_ws;
  float* W23    = (float*)(ws + 0x00000000);  // 120 KB [1024][30] k-major
  float* W123   = (float*)(ws + 0x00020000);  // 180 KB [1536][30] k-major
  float* beff23 = (float*)(ws + 0x00050000);  // 120 B
  float* btot   = (float*)(ws + 0x00050200);  // 120 B
  float* part   = (float*)(ws + 0x00051000);  // 10 KB [512][5]

  prep1<<<121, 256, 0, stream>>>(W2, W3, b2, b3, W23, beff23);
  prep2<<<181, 256, 0, stream>>>(W1, b1, W23, beff23, W123, btot);
  loss_kernel<<<NBLK, 256, 0, stream>>>(tok, pool, npos, W123, btot, labels, part);
  finalize_kernel<<<1, 256, 0, stream>>>(part, out);
}